// Round 1
// baseline (17928.308 us; speedup 1.0000x reference)
//
#include <hip/hip_runtime.h>
#include <math.h>

#define NA 100000
#define NB 100000
#define FT 128
#define H1 128
#define H2 64
#define OUTD 64

// ---------------- zero fill ----------------
__global__ __launch_bounds__(256) void zero_k(float4* __restrict__ p, int n4) {
    int i = blockIdx.x * 256 + threadIdx.x;
    if (i < n4) p[i] = make_float4(0.f, 0.f, 0.f, 0.f);
}

// ---------------- GEMM: C = act(A@W + bias [+ C]) ----------------
// A: M x KT row-major (lda == KT). W: KT x Nfull row-major. C: M x ldc.
// Tile: BM=64 rows x BN=64 cols, 256 threads, 8x2 per-thread register tile.
template<int KT, bool BIAS, bool ACT, bool ACCUM>
__global__ __launch_bounds__(256) void gemm_k(
    const float* __restrict__ A,
    const float* __restrict__ W,
    const float* __restrict__ bias,
    float* __restrict__ C,
    int M, int Nfull, int ldc)
{
    constexpr int BM = 64;
    constexpr int BN = 64;
    __shared__ float Ash[BM * KT];       // [r][k] row-major
    __shared__ float Wsh[KT * BN];       // [k][n^ (k&31)] xor-swizzled

    const int t = threadIdx.x;
    const int row0 = blockIdx.x * BM;
    const int n0 = blockIdx.y * BN;

    // stage A tile (row-guarded)
    for (int idx = t * 4; idx < BM * KT; idx += 256 * 4) {
        const int r = idx / KT;
        float4 v = make_float4(0.f, 0.f, 0.f, 0.f);
        if (row0 + r < M) v = *(const float4*)(A + (size_t)(row0 + r) * KT + (idx - r * KT));
        *(float4*)(Ash + idx) = v;
    }
    // stage W tile, xor-swizzle column within 32 to kill bank conflicts
    for (int idx = t; idx < KT * BN; idx += 256) {
        const int k = idx >> 6;          // BN == 64
        const int n = idx & 63;
        Wsh[k * BN + (n ^ (k & 31))] = W[(size_t)k * Nfull + n0 + n];
    }
    __syncthreads();

    const int c  = t & 31;
    const int r0 = (t >> 5) * 8;

    float acc[8][2];
#pragma unroll
    for (int i = 0; i < 8; i++) { acc[i][0] = 0.f; acc[i][1] = 0.f; }

#pragma unroll 4
    for (int k = 0; k < KT; k += 4) {
        float4 a[8];
#pragma unroll
        for (int i = 0; i < 8; i++) a[i] = *(const float4*)(Ash + (r0 + i) * KT + k);
        float w[4][2];
#pragma unroll
        for (int kk = 0; kk < 4; kk++) {
            const int sw = (k + kk) & 31;
#pragma unroll
            for (int j = 0; j < 2; j++)
                w[kk][j] = Wsh[(k + kk) * BN + ((c + 32 * j) ^ sw)];
        }
#pragma unroll
        for (int i = 0; i < 8; i++) {
            acc[i][0] += a[i].x * w[0][0]; acc[i][1] += a[i].x * w[0][1];
            acc[i][0] += a[i].y * w[1][0]; acc[i][1] += a[i].y * w[1][1];
            acc[i][0] += a[i].z * w[2][0]; acc[i][1] += a[i].z * w[2][1];
            acc[i][0] += a[i].w * w[3][0]; acc[i][1] += a[i].w * w[3][1];
        }
    }

#pragma unroll
    for (int i = 0; i < 8; i++) {
        const int row = row0 + r0 + i;
        if (row < M) {
#pragma unroll
            for (int j = 0; j < 2; j++) {
                const int col = n0 + c + 32 * j;
                float v = acc[i][j];
                if (BIAS)  v += bias[col];
                if (ACCUM) v += C[(size_t)row * ldc + col];
                if (ACT)   v = (v > 0.f) ? v : 0.01f * v;
                C[(size_t)row * ldc + col] = v;
            }
        }
    }
}

// ---------------- SpMM (COO, atomic scatter) ----------------
// out[row] += val * X[col]; one thread per (edge, 4 floats). out pre-zeroed.
template<int F>
__global__ __launch_bounds__(256) void spmm_k(
    const int* __restrict__ rows, const int* __restrict__ cols,
    const float* __restrict__ vals, const float* __restrict__ X,
    float* __restrict__ out, int E)
{
    constexpr int TPE = F / 4;
    const int gid = blockIdx.x * 256 + threadIdx.x;
    const int e = gid / TPE;
    if (e >= E) return;
    const int cc = gid - e * TPE;
    const int r  = rows[e];
    const int ci = cols[e];
    const float v = vals[e];
    const float4 x = *(const float4*)(X + (size_t)ci * F + cc * 4);
    float* dst = out + (size_t)r * F + cc * 4;
    atomicAdd(dst + 0, v * x.x);
    atomicAdd(dst + 1, v * x.y);
    atomicAdd(dst + 2, v * x.z);
    atomicAdd(dst + 3, v * x.w);
}

// ---------------- elementwise bias + LeakyReLU ----------------
template<int F>
__global__ __launch_bounds__(256) void bias_act_k(
    float* __restrict__ X, const float* __restrict__ b, int N)
{
    constexpr int F4 = F / 4;
    const int gid = blockIdx.x * 256 + threadIdx.x;   // over N*F/4
    if (gid >= N * F4) return;
    const int col4 = (gid & (F4 - 1)) * 4;
    float4 x = *(float4*)(X + (size_t)gid * 4);
    x.x += b[col4 + 0]; x.y += b[col4 + 1]; x.z += b[col4 + 2]; x.w += b[col4 + 3];
    x.x = x.x > 0.f ? x.x : 0.01f * x.x;
    x.y = x.y > 0.f ? x.y : 0.01f * x.y;
    x.z = x.z > 0.f ? x.z : 0.01f * x.z;
    x.w = x.w > 0.f ? x.w : 0.01f * x.w;
    *(float4*)(X + (size_t)gid * 4) = x;
}

// ---------------- semantic attention over P=2 relations ----------------
// w_p[n] = sum_j tanh( (g_p[n,:] @ W1)[j] + b1[j] ) * W2[j]
// beta = softmax_p(w); e[n,:] = beta0*g0[n,:] + beta1*g1[n,:]
// one wave (64 lanes) per node.
template<int D, int H>
__global__ __launch_bounds__(256) void att_k(
    const float* __restrict__ g0, const float* __restrict__ g1,
    const float* __restrict__ W1, const float* __restrict__ b1,
    const float* __restrict__ W2, float* __restrict__ eo, int N)
{
    const int gid  = blockIdx.x * 256 + threadIdx.x;
    const int node = gid >> 6;
    const int lane = threadIdx.x & 63;
    if (node >= N) return;
    constexpr int NH = 64 / H;     // lanes sharing one j
    constexpr int KC = D / NH;     // k-chunk per lane
    const int j = lane & (H - 1);
    const int h = lane / H;

    float wsc[2];
#pragma unroll
    for (int p = 0; p < 2; p++) {
        const float* g = (p == 0 ? g0 : g1) + (size_t)node * D;
        float s = 0.f;
        for (int k = h * KC; k < (h + 1) * KC; k++)
            s += g[k] * W1[k * H + j];
        s += __shfl_xor(s, H);
        if (NH == 4) s += __shfl_xor(s, 2 * H);
        float tt = tanhf(s + b1[j]) * W2[j];
#pragma unroll
        for (int m = 1; m < H; m <<= 1) tt += __shfl_xor(tt, m);
        wsc[p] = tt;
    }
    const float mx = fmaxf(wsc[0], wsc[1]);
    const float e0 = expf(wsc[0] - mx), e1 = expf(wsc[1] - mx);
    const float inv = 1.f / (e0 + e1);
    const float be0 = e0 * inv, be1 = e1 * inv;
    const float* G0 = g0 + (size_t)node * D;
    const float* G1 = g1 + (size_t)node * D;
    float* EO = eo + (size_t)node * D;
#pragma unroll
    for (int k = lane; k < D; k += 64)
        EO[k] = be0 * G0[k] + be1 * G1[k];
}

// ---------------- launch ----------------
extern "C" void kernel_launch(void* const* d_in, const int* in_sizes, int n_in,
                              void* d_out, int out_size, void* d_ws, size_t ws_size,
                              hipStream_t stream)
{
    const float* feat = (const float*)d_in[0];
    const int*   row_aa = (const int*)d_in[1];
    const int*   col_aa = (const int*)d_in[2];
    const float* val_aa = (const float*)d_in[3];
    const int*   row_ab = (const int*)d_in[4];
    const int*   col_ab = (const int*)d_in[5];
    const float* val_ab = (const float*)d_in[6];
    const int*   row_ba = (const int*)d_in[7];
    const int*   col_ba = (const int*)d_in[8];
    const float* val_ba = (const float*)d_in[9];
    const int*   row_bb = (const int*)d_in[10];
    const int*   col_bb = (const int*)d_in[11];
    const float* val_bb = (const float*)d_in[12];
    const float* W0_aa = (const float*)d_in[13]; const float* b0_aa = (const float*)d_in[14];
    const float* W1_aa = (const float*)d_in[15]; const float* b1_aa = (const float*)d_in[16];
    const float* W0_ab = (const float*)d_in[17]; const float* b0_ab = (const float*)d_in[18];
    const float* W1_ab = (const float*)d_in[19]; const float* b1_ab = (const float*)d_in[20];
    const float* W0_ba = (const float*)d_in[21]; const float* b0_ba = (const float*)d_in[22];
    const float* W1_ba = (const float*)d_in[23]; const float* b1_ba = (const float*)d_in[24];
    const float* W0_bb = (const float*)d_in[25]; const float* b0_bb = (const float*)d_in[26];
    const float* W1_bb = (const float*)d_in[27]; const float* b1_bb = (const float*)d_in[28];
    const float* att0_a_W1 = (const float*)d_in[29];
    const float* att0_a_b1 = (const float*)d_in[30];
    const float* att0_a_W2 = (const float*)d_in[31];
    const float* att1_a_W1 = (const float*)d_in[32];
    const float* att1_a_b1 = (const float*)d_in[33];
    const float* att1_a_W2 = (const float*)d_in[34];
    const float* Wf_a = (const float*)d_in[35]; const float* bf_a = (const float*)d_in[36];
    const float* att0_b_W1 = (const float*)d_in[37];
    const float* att0_b_b1 = (const float*)d_in[38];
    const float* att0_b_W2 = (const float*)d_in[39];
    const float* att1_b_W1 = (const float*)d_in[40];
    const float* att1_b_b1 = (const float*)d_in[41];
    const float* att1_b_W2 = (const float*)d_in[42];
    const float* Wf_b = (const float*)d_in[43]; const float* bf_b = (const float*)d_in[44];

    const int E_aa = in_sizes[1], E_ab = in_sizes[4], E_ba = in_sizes[7], E_bb = in_sizes[10];

    // workspace: 5 regions of 12.8M floats = 256 MB total
    const size_t R = (size_t)12800000;
    if (ws_size < 5 * R * sizeof(float)) return;   // fail visibly rather than corrupt
    float* ws   = (float*)d_ws;
    float* Btmp = ws;            // spmm accumulators / layer1 Y / u_a,u_b overlay
    float* B0   = ws + R;        // g (relation 0 of current type)
    float* B1   = ws + 2 * R;    // g (relation 1)
    float* C0   = ws + 3 * R;    // e1_a
    float* C1   = ws + 4 * R;    // e1_b
    float* D0   = Btmp;              // u_a (NA x 64)
    float* D1   = Btmp + 6400000;    // u_b (NB x 64)
    float* out  = (float*)d_out;

    const float* fa = feat;
    const float* fb = feat + (size_t)NA * FT;

    const dim3 blk(256);
    const dim3 gG(1563, 2);          // GEMM grid for M=100000, N=128
    const dim3 gG64(1563, 1);        // GEMM grid for M=100000, N=64
    const int z128 = (NA * FT / 4 + 255) / 256;     // zero-fill blocks, 128-wide
    const int z64  = (NA * H2 / 4 + 255) / 256;     // zero-fill blocks, 64-wide
    const int sp128 = (int)(((long long)E_aa * 32 + 255) / 256);  // all E equal
    const int sp64  = (int)(((long long)E_aa * 16 + 255) / 256);
    const int ba64  = (NA * H2 / 4 + 255) / 256;
    const int attg  = (NA + 3) / 4;  // one wave/node, 4 waves/block

    // ================= layer 0, type a =================
    // relation aa: S = spmm(aa, fa); g = lrelu(S@W0_aa + b0_aa)
    zero_k<<<z128, blk, 0, stream>>>((float4*)Btmp, NA * FT / 4);
    spmm_k<128><<<sp128, blk, 0, stream>>>(row_aa, col_aa, val_aa, fa, Btmp, E_aa);
    gemm_k<128, true, true, false><<<gG, blk, 0, stream>>>(Btmp, W0_aa, b0_aa, B0, NA, 128, 128);
    // relation ab
    zero_k<<<z128, blk, 0, stream>>>((float4*)Btmp, NA * FT / 4);
    spmm_k<128><<<sp128, blk, 0, stream>>>(row_ab, col_ab, val_ab, fb, Btmp, E_ab);
    gemm_k<128, true, true, false><<<gG, blk, 0, stream>>>(Btmp, W0_ab, b0_ab, B1, NA, 128, 128);
    // semantic attention -> e1_a
    att_k<128, 32><<<attg, blk, 0, stream>>>(B0, B1, att0_a_W1, att0_a_b1, att0_a_W2, C0, NA);

    // ================= layer 0, type b =================
    zero_k<<<z128, blk, 0, stream>>>((float4*)Btmp, NB * FT / 4);
    spmm_k<128><<<sp128, blk, 0, stream>>>(row_ba, col_ba, val_ba, fa, Btmp, E_ba);
    gemm_k<128, true, true, false><<<gG, blk, 0, stream>>>(Btmp, W0_ba, b0_ba, B0, NB, 128, 128);
    zero_k<<<z128, blk, 0, stream>>>((float4*)Btmp, NB * FT / 4);
    spmm_k<128><<<sp128, blk, 0, stream>>>(row_bb, col_bb, val_bb, fb, Btmp, E_bb);
    gemm_k<128, true, true, false><<<gG, blk, 0, stream>>>(Btmp, W0_bb, b0_bb, B1, NB, 128, 128);
    att_k<128, 32><<<attg, blk, 0, stream>>>(B0, B1, att0_b_W1, att0_b_b1, att0_b_W2, C1, NB);

    // ================= layer 1, type a =================
    // pre-transform: spmm(E, e1)@W1 == spmm(E, e1@W1)  -> spmm at width 64
    float* Y0 = Btmp;              // NA x 64
    float* Y1 = Btmp + 6400000;    // NB x 64
    gemm_k<128, false, false, false><<<gG64, blk, 0, stream>>>(C0, W1_aa, nullptr, Y0, NA, 64, 64);
    zero_k<<<z64, blk, 0, stream>>>((float4*)B0, NA * H2 / 4);
    spmm_k<64><<<sp64, blk, 0, stream>>>(row_aa, col_aa, val_aa, Y0, B0, E_aa);
    bias_act_k<64><<<ba64, blk, 0, stream>>>(B0, b1_aa, NA);

    gemm_k<128, false, false, false><<<gG64, blk, 0, stream>>>(C1, W1_ab, nullptr, Y1, NB, 64, 64);
    zero_k<<<z64, blk, 0, stream>>>((float4*)B1, NA * H2 / 4);
    spmm_k<64><<<sp64, blk, 0, stream>>>(row_ab, col_ab, val_ab, Y1, B1, E_ab);
    bias_act_k<64><<<ba64, blk, 0, stream>>>(B1, b1_ab, NA);

    att_k<64, 16><<<attg, blk, 0, stream>>>(B0, B1, att1_a_W1, att1_a_b1, att1_a_W2, D0, NA);

    // ================= layer 1, type b =================
    gemm_k<128, false, false, false><<<gG64, blk, 0, stream>>>(C0, W1_ba, nullptr, Y1, NA, 64, 64);
    zero_k<<<z64, blk, 0, stream>>>((float4*)B0, NB * H2 / 4);
    spmm_k<64><<<sp64, blk, 0, stream>>>(row_ba, col_ba, val_ba, Y1, B0, E_ba);
    bias_act_k<64><<<ba64, blk, 0, stream>>>(B0, b1_ba, NB);

    gemm_k<128, false, false, false><<<gG64, blk, 0, stream>>>(C1, W1_bb, nullptr, Y1, NB, 64, 64);
    zero_k<<<z64, blk, 0, stream>>>((float4*)B1, NB * H2 / 4);
    spmm_k<64><<<sp64, blk, 0, stream>>>(row_bb, col_bb, val_bb, Y1, B1, E_bb);
    bias_act_k<64><<<ba64, blk, 0, stream>>>(B1, b1_bb, NB);

    att_k<64, 16><<<attg, blk, 0, stream>>>(B0, B1, att1_b_W1, att1_b_b1, att1_b_W2, D1, NB);

    // ================= final projection =================
    // out_a = [u_a, fa] @ Wf_a + bf_a  (split K: 64 then 128 accumulate)
    gemm_k<64, true, false, false><<<gG64, blk, 0, stream>>>(D0, Wf_a, bf_a, out, NA, 64, 64);
    gemm_k<128, false, false, true><<<gG64, blk, 0, stream>>>(fa, Wf_a + 64 * 64, nullptr, out, NA, 64, 64);
    gemm_k<64, true, false, false><<<gG64, blk, 0, stream>>>(D1, Wf_b, bf_b, out + (size_t)NA * OUTD, NB, 64, 64);
    gemm_k<128, false, false, true><<<gG64, blk, 0, stream>>>(fb, Wf_b + 64 * 64, nullptr, out + (size_t)NA * OUTD, NB, 64, 64);
}

// Round 2
// 3359.050 us; speedup vs baseline: 5.3373x; 5.3373x over previous
//
#include <hip/hip_runtime.h>
#include <math.h>

#define NA 100000
#define NB 100000
#define NROW 100000   // all four relations have 100000 output rows
#define FT 128
#define H1 128
#define H2 64
#define OUTD 64

// ---------------- zero fill (used for CSR count arrays) ----------------
__global__ __launch_bounds__(256) void zero_k(float4* __restrict__ p, int n4) {
    int i = blockIdx.x * 256 + threadIdx.x;
    if (i < n4) p[i] = make_float4(0.f, 0.f, 0.f, 0.f);
}

// ---------------- CSR build: histogram ----------------
__global__ __launch_bounds__(256) void hist_k(const int* __restrict__ rows,
                                              int* __restrict__ cnt, int E) {
    int i = blockIdx.x * 256 + threadIdx.x;
    if (i < E) atomicAdd(&cnt[rows[i]], 1);
}

// ---------------- CSR build: exclusive scan (one block per relation) ----------------
__global__ __launch_bounds__(1024) void scan_k(const int* __restrict__ cnt4,
                                               int* __restrict__ rp4,
                                               int* __restrict__ cur4, int N) {
    __shared__ int sh[1024];
    const int r = blockIdx.x;
    const int* cnt = cnt4 + (size_t)r * N;
    int* rp  = rp4 + (size_t)r * (N + 1);
    int* cur = cur4 + (size_t)r * N;
    const int t = threadIdx.x;
    const int chunk = (N + 1023) / 1024;
    const int lo = t * chunk;
    const int hi = min(N, lo + chunk);
    int s = 0;
    for (int i = lo; i < hi; i++) s += cnt[i];
    sh[t] = s;
    __syncthreads();
    for (int off = 1; off < 1024; off <<= 1) {
        int v = (t >= off) ? sh[t - off] : 0;
        __syncthreads();
        sh[t] += v;
        __syncthreads();
    }
    int base = (t == 0) ? 0 : sh[t - 1];
    for (int i = lo; i < hi; i++) {
        rp[i] = base; cur[i] = base;
        base += cnt[i];
    }
    if (t == 1023) rp[N] = sh[1023];
}

// ---------------- CSR build: scatter (col,val) into row-sorted order ----------------
__global__ __launch_bounds__(256) void scatter_k(const int* __restrict__ rows,
                                                 const int* __restrict__ cols,
                                                 const float* __restrict__ vals,
                                                 int* __restrict__ cur,
                                                 int* __restrict__ colsS,
                                                 float* __restrict__ valsS, int E) {
    int i = blockIdx.x * 256 + threadIdx.x;
    if (i >= E) return;
    int r = rows[i];
    int pos = atomicAdd(&cur[r], 1);
    colsS[pos] = cols[i];
    valsS[pos] = vals[i];
}

// ---------------- SpMM (CSR gather), fused bias + LeakyReLU ----------------
// One wave per output row. F=128: float2/lane; F=64: float/lane.
// out[r,:] = lrelu( sum_j val_j * X[col_j,:] + bias )
template<int F>
__global__ __launch_bounds__(256) void spmm_csr_k(
    const int* __restrict__ rp, const int* __restrict__ colsS,
    const float* __restrict__ valsS, const float* __restrict__ X,
    const float* __restrict__ bias, float* __restrict__ out, int N)
{
    const int wid  = (blockIdx.x * 256 + threadIdx.x) >> 6;
    const int lane = threadIdx.x & 63;
    if (wid >= N) return;
    const int s = rp[wid];
    const int e = rp[wid + 1];

    if (F == 128) {
        float ax = 0.f, ay = 0.f;
        int j = s;
        for (; j + 3 < e; j += 4) {
            int c0 = colsS[j], c1 = colsS[j+1], c2 = colsS[j+2], c3 = colsS[j+3];
            float v0 = valsS[j], v1 = valsS[j+1], v2 = valsS[j+2], v3 = valsS[j+3];
            float2 x0 = *(const float2*)(X + (size_t)c0 * F + 2 * lane);
            float2 x1 = *(const float2*)(X + (size_t)c1 * F + 2 * lane);
            float2 x2 = *(const float2*)(X + (size_t)c2 * F + 2 * lane);
            float2 x3 = *(const float2*)(X + (size_t)c3 * F + 2 * lane);
            ax += v0 * x0.x + v1 * x1.x + v2 * x2.x + v3 * x3.x;
            ay += v0 * x0.y + v1 * x1.y + v2 * x2.y + v3 * x3.y;
        }
        for (; j < e; j++) {
            int c = colsS[j]; float v = valsS[j];
            float2 x = *(const float2*)(X + (size_t)c * F + 2 * lane);
            ax += v * x.x; ay += v * x.y;
        }
        ax += bias[2 * lane];
        ay += bias[2 * lane + 1];
        ax = ax > 0.f ? ax : 0.01f * ax;
        ay = ay > 0.f ? ay : 0.01f * ay;
        float2* dst = (float2*)(out + (size_t)wid * F + 2 * lane);
        *dst = make_float2(ax, ay);
    } else {
        float a = 0.f;
        int j = s;
        for (; j + 3 < e; j += 4) {
            int c0 = colsS[j], c1 = colsS[j+1], c2 = colsS[j+2], c3 = colsS[j+3];
            float v0 = valsS[j], v1 = valsS[j+1], v2 = valsS[j+2], v3 = valsS[j+3];
            a += v0 * X[(size_t)c0 * F + lane] + v1 * X[(size_t)c1 * F + lane]
               + v2 * X[(size_t)c2 * F + lane] + v3 * X[(size_t)c3 * F + lane];
        }
        for (; j < e; j++)
            a += valsS[j] * X[(size_t)colsS[j] * F + lane];
        a += bias[lane];
        a = a > 0.f ? a : 0.01f * a;
        out[(size_t)wid * F + lane] = a;
    }
}

// ---------------- GEMM: C = [act](A@W + [bias] [+ C]) ----------------
// A: M x KT row-major. W: KT x Nfull row-major. C: M x ldc.
// Tile: 64x64, 256 threads, 8x2 register tile, xor-swizzled W tile.
template<int KT, bool BIAS, bool ACT, bool ACCUM>
__global__ __launch_bounds__(256) void gemm_k(
    const float* __restrict__ A,
    const float* __restrict__ W,
    const float* __restrict__ bias,
    float* __restrict__ C,
    int M, int Nfull, int ldc)
{
    constexpr int BM = 64;
    constexpr int BN = 64;
    __shared__ float Ash[BM * KT];
    __shared__ float Wsh[KT * BN];

    const int t = threadIdx.x;
    const int row0 = blockIdx.x * BM;
    const int n0 = blockIdx.y * BN;

    for (int idx = t * 4; idx < BM * KT; idx += 256 * 4) {
        const int r = idx / KT;
        float4 v = make_float4(0.f, 0.f, 0.f, 0.f);
        if (row0 + r < M) v = *(const float4*)(A + (size_t)(row0 + r) * KT + (idx - r * KT));
        *(float4*)(Ash + idx) = v;
    }
    for (int idx = t; idx < KT * BN; idx += 256) {
        const int k = idx >> 6;
        const int n = idx & 63;
        Wsh[k * BN + (n ^ (k & 31))] = W[(size_t)k * Nfull + n0 + n];
    }
    __syncthreads();

    const int c  = t & 31;
    const int r0 = (t >> 5) * 8;

    float acc[8][2];
#pragma unroll
    for (int i = 0; i < 8; i++) { acc[i][0] = 0.f; acc[i][1] = 0.f; }

#pragma unroll 4
    for (int k = 0; k < KT; k += 4) {
        float4 a[8];
#pragma unroll
        for (int i = 0; i < 8; i++) a[i] = *(const float4*)(Ash + (r0 + i) * KT + k);
        float w[4][2];
#pragma unroll
        for (int kk = 0; kk < 4; kk++) {
            const int sw = (k + kk) & 31;
#pragma unroll
            for (int j = 0; j < 2; j++)
                w[kk][j] = Wsh[(k + kk) * BN + ((c + 32 * j) ^ sw)];
        }
#pragma unroll
        for (int i = 0; i < 8; i++) {
            acc[i][0] += a[i].x * w[0][0]; acc[i][1] += a[i].x * w[0][1];
            acc[i][0] += a[i].y * w[1][0]; acc[i][1] += a[i].y * w[1][1];
            acc[i][0] += a[i].z * w[2][0]; acc[i][1] += a[i].z * w[2][1];
            acc[i][0] += a[i].w * w[3][0]; acc[i][1] += a[i].w * w[3][1];
        }
    }

#pragma unroll
    for (int i = 0; i < 8; i++) {
        const int row = row0 + r0 + i;
        if (row < M) {
#pragma unroll
            for (int j = 0; j < 2; j++) {
                const int col = n0 + c + 32 * j;
                float v = acc[i][j];
                if (BIAS)  v += bias[col];
                if (ACCUM) v += C[(size_t)row * ldc + col];
                if (ACT)   v = (v > 0.f) ? v : 0.01f * v;
                C[(size_t)row * ldc + col] = v;
            }
        }
    }
}

// ---------------- semantic attention over P=2 relations ----------------
// one wave per node; safe to run in-place (eo == g0).
template<int D, int H>
__global__ __launch_bounds__(256) void att_k(
    const float* __restrict__ g0, const float* __restrict__ g1,
    const float* __restrict__ W1, const float* __restrict__ b1,
    const float* __restrict__ W2, float* __restrict__ eo, int N)
{
    const int gid  = blockIdx.x * 256 + threadIdx.x;
    const int node = gid >> 6;
    const int lane = threadIdx.x & 63;
    if (node >= N) return;
    constexpr int NH = 64 / H;
    constexpr int KC = D / NH;
    const int j = lane & (H - 1);
    const int h = lane / H;

    float wsc[2];
#pragma unroll
    for (int p = 0; p < 2; p++) {
        const float* g = (p == 0 ? g0 : g1) + (size_t)node * D;
        float s = 0.f;
        for (int k = h * KC; k < (h + 1) * KC; k++)
            s += g[k] * W1[k * H + j];
        s += __shfl_xor(s, H);
        if (NH == 4) s += __shfl_xor(s, 2 * H);
        float tt = tanhf(s + b1[j]) * W2[j];
#pragma unroll
        for (int m = 1; m < H; m <<= 1) tt += __shfl_xor(tt, m);
        wsc[p] = tt;
    }
    const float mx = fmaxf(wsc[0], wsc[1]);
    const float e0 = expf(wsc[0] - mx), e1 = expf(wsc[1] - mx);
    const float inv = 1.f / (e0 + e1);
    const float be0 = e0 * inv, be1 = e1 * inv;
    const float* G0 = g0 + (size_t)node * D;
    const float* G1 = g1 + (size_t)node * D;
    float* EO = eo + (size_t)node * D;
#pragma unroll
    for (int k = lane; k < D; k += 64)
        EO[k] = be0 * G0[k] + be1 * G1[k];
}

// ---------------- launch ----------------
extern "C" void kernel_launch(void* const* d_in, const int* in_sizes, int n_in,
                              void* d_out, int out_size, void* d_ws, size_t ws_size,
                              hipStream_t stream)
{
    const float* feat = (const float*)d_in[0];
    const int*   row_aa = (const int*)d_in[1];
    const int*   col_aa = (const int*)d_in[2];
    const float* val_aa = (const float*)d_in[3];
    const int*   row_ab = (const int*)d_in[4];
    const int*   col_ab = (const int*)d_in[5];
    const float* val_ab = (const float*)d_in[6];
    const int*   row_ba = (const int*)d_in[7];
    const int*   col_ba = (const int*)d_in[8];
    const float* val_ba = (const float*)d_in[9];
    const int*   row_bb = (const int*)d_in[10];
    const int*   col_bb = (const int*)d_in[11];
    const float* val_bb = (const float*)d_in[12];
    const float* W0_aa = (const float*)d_in[13]; const float* b0_aa = (const float*)d_in[14];
    const float* W1_aa = (const float*)d_in[15]; const float* b1_aa = (const float*)d_in[16];
    const float* W0_ab = (const float*)d_in[17]; const float* b0_ab = (const float*)d_in[18];
    const float* W1_ab = (const float*)d_in[19]; const float* b1_ab = (const float*)d_in[20];
    const float* W0_ba = (const float*)d_in[21]; const float* b0_ba = (const float*)d_in[22];
    const float* W1_ba = (const float*)d_in[23]; const float* b1_ba = (const float*)d_in[24];
    const float* W0_bb = (const float*)d_in[25]; const float* b0_bb = (const float*)d_in[26];
    const float* W1_bb = (const float*)d_in[27]; const float* b1_bb = (const float*)d_in[28];
    const float* att0_a_W1 = (const float*)d_in[29];
    const float* att0_a_b1 = (const float*)d_in[30];
    const float* att0_a_W2 = (const float*)d_in[31];
    const float* att1_a_W1 = (const float*)d_in[32];
    const float* att1_a_b1 = (const float*)d_in[33];
    const float* att1_a_W2 = (const float*)d_in[34];
    const float* Wf_a = (const float*)d_in[35]; const float* bf_a = (const float*)d_in[36];
    const float* att0_b_W1 = (const float*)d_in[37];
    const float* att0_b_b1 = (const float*)d_in[38];
    const float* att0_b_W2 = (const float*)d_in[39];
    const float* att1_b_W1 = (const float*)d_in[40];
    const float* att1_b_b1 = (const float*)d_in[41];
    const float* att1_b_W2 = (const float*)d_in[42];
    const float* Wf_b = (const float*)d_in[43]; const float* bf_b = (const float*)d_in[44];

    const int E_r[4] = { in_sizes[1], in_sizes[4], in_sizes[7], in_sizes[10] };
    const int* rows_r[4] = { row_aa, row_ab, row_ba, row_bb };
    const int* cols_r[4] = { col_aa, col_ab, col_ba, col_bb };
    const float* vals_r[4] = { val_aa, val_ab, val_ba, val_bb };

    // ---------------- workspace layout ----------------
    // floats: A0,A1,A2 = 3 x 12.8M (153.6 MB). A3 = d_out (12.8M floats).
    // ints:   rp4 (4x100001), cnt4 (4x100000), cur4 (4x100000),
    //         colsS (sum E), valsS (sum E floats)
    const size_t RSZ = (size_t)12800000;
    size_t Etot = (size_t)E_r[0] + E_r[1] + E_r[2] + E_r[3];
    size_t need = (3 * RSZ + (size_t)4 * (NROW + 1) + 8 * (size_t)NROW + 2 * Etot) * 4;
    if (ws_size < need) return;

    float* ws = (float*)d_ws;
    float* A0 = ws;
    float* A1 = ws + RSZ;
    float* A2 = ws + 2 * RSZ;
    float* A3 = (float*)d_out;            // e1_b lives here until final projection
    int*   rp4  = (int*)(ws + 3 * RSZ);
    int*   cnt4 = rp4 + (size_t)4 * (NROW + 1);
    int*   cur4 = cnt4 + (size_t)4 * NROW;
    int*   colsS = cur4 + (size_t)4 * NROW;
    float* valsS = (float*)(colsS + Etot);

    size_t eoff[4];
    eoff[0] = 0; eoff[1] = eoff[0] + E_r[0];
    eoff[2] = eoff[1] + E_r[1]; eoff[3] = eoff[2] + E_r[2];

    float* out = (float*)d_out;
    const float* fa = feat;
    const float* fb = feat + (size_t)NA * FT;

    const dim3 blk(256);
    const dim3 gG(1563, 2);       // GEMM M=100000, N=128
    const dim3 gG64(1563, 1);     // GEMM M=100000, N=64
    const int spg = (NROW * 64 + 255) / 256;   // spmm: one wave per row

    // ================= build CSR for all 4 relations =================
    zero_k<<<(4 * NROW / 4 + 255) / 256, blk, 0, stream>>>((float4*)cnt4, 4 * NROW / 4);
    for (int r = 0; r < 4; r++)
        hist_k<<<(E_r[r] + 255) / 256, blk, 0, stream>>>(rows_r[r], cnt4 + (size_t)r * NROW, E_r[r]);
    scan_k<<<4, 1024, 0, stream>>>(cnt4, rp4, cur4, NROW);
    for (int r = 0; r < 4; r++)
        scatter_k<<<(E_r[r] + 255) / 256, blk, 0, stream>>>(
            rows_r[r], cols_r[r], vals_r[r], cur4 + (size_t)r * NROW,
            colsS + eoff[r], valsS + eoff[r], E_r[r]);

    const int* rp_aa = rp4;
    const int* rp_ab = rp4 + (NROW + 1);
    const int* rp_ba = rp4 + 2 * (NROW + 1);
    const int* rp_bb = rp4 + 3 * (NROW + 1);
    const int* cs_aa = colsS + eoff[0]; const float* vs_aa = valsS + eoff[0];
    const int* cs_ab = colsS + eoff[1]; const float* vs_ab = valsS + eoff[1];
    const int* cs_ba = colsS + eoff[2]; const float* vs_ba = valsS + eoff[2];
    const int* cs_bb = colsS + eoff[3]; const float* vs_bb = valsS + eoff[3];

    // ================= layer 0, type a =================
    // g = lrelu(spmm(r, x@W0) + b0)   [GEMM-first, fused epilogue in spmm]
    gemm_k<128, false, false, false><<<gG, blk, 0, stream>>>(fa, W0_aa, nullptr, A0, NA, 128, 128);
    spmm_csr_k<128><<<spg, blk, 0, stream>>>(rp_aa, cs_aa, vs_aa, A0, b0_aa, A1, NA);
    gemm_k<128, false, false, false><<<gG, blk, 0, stream>>>(fb, W0_ab, nullptr, A0, NB, 128, 128);
    spmm_csr_k<128><<<spg, blk, 0, stream>>>(rp_ab, cs_ab, vs_ab, A0, b0_ab, A2, NA);
    att_k<128, 32><<<(NA + 3) / 4, blk, 0, stream>>>(A1, A2, att0_a_W1, att0_a_b1, att0_a_W2, A1, NA);
    // e1_a in A1

    // ================= layer 0, type b =================
    gemm_k<128, false, false, false><<<gG, blk, 0, stream>>>(fa, W0_ba, nullptr, A0, NA, 128, 128);
    spmm_csr_k<128><<<spg, blk, 0, stream>>>(rp_ba, cs_ba, vs_ba, A0, b0_ba, A3, NB);
    gemm_k<128, false, false, false><<<gG, blk, 0, stream>>>(fb, W0_bb, nullptr, A0, NB, 128, 128);
    spmm_csr_k<128><<<spg, blk, 0, stream>>>(rp_bb, cs_bb, vs_bb, A0, b0_bb, A2, NB);
    att_k<128, 32><<<(NB + 3) / 4, blk, 0, stream>>>(A3, A2, att0_b_W1, att0_b_b1, att0_b_W2, A3, NB);
    // e1_b in A3 (= d_out region)

    float* A0lo = A0;            float* A0hi = A0 + RSZ / 2;
    float* A2lo = A2;            float* A2hi = A2 + RSZ / 2;

    // ================= layer 1, type a =================
    // g = lrelu(spmm(r, e1@W1) + b1)
    gemm_k<128, false, false, false><<<gG64, blk, 0, stream>>>(A1, W1_aa, nullptr, A0lo, NA, 64, 64);
    spmm_csr_k<64><<<spg, blk, 0, stream>>>(rp_aa, cs_aa, vs_aa, A0lo, b1_aa, A0hi, NA);
    gemm_k<128, false, false, false><<<gG64, blk, 0, stream>>>(A3, W1_ab, nullptr, A2lo, NB, 64, 64);
    spmm_csr_k<64><<<spg, blk, 0, stream>>>(rp_ab, cs_ab, vs_ab, A2lo, b1_ab, A2hi, NA);
    att_k<64, 16><<<(NA + 3) / 4, blk, 0, stream>>>(A0hi, A2hi, att1_a_W1, att1_a_b1, att1_a_W2, A0hi, NA);
    // u_a in A0hi

    // ================= layer 1, type b =================
    gemm_k<128, false, false, false><<<gG64, blk, 0, stream>>>(A1, W1_ba, nullptr, A2lo, NA, 64, 64);
    spmm_csr_k<64><<<spg, blk, 0, stream>>>(rp_ba, cs_ba, vs_ba, A2lo, b1_ba, A2hi, NB);
    gemm_k<128, false, false, false><<<gG64, blk, 0, stream>>>(A3, W1_bb, nullptr, A2lo, NB, 64, 64);
    // (e1_b consumed; d_out free from here on)
    spmm_csr_k<64><<<spg, blk, 0, stream>>>(rp_bb, cs_bb, vs_bb, A2lo, b1_bb, A0lo, NB);
    att_k<64, 16><<<(NB + 3) / 4, blk, 0, stream>>>(A2hi, A0lo, att1_b_W1, att1_b_b1, att1_b_W2, A2hi, NB);
    // u_b in A2hi

    // ================= final projection =================
    // out = [u, feat] @ Wf + bf   (split K: 64 with bias, then 128 accumulating)
    gemm_k<64,  true,  false, false><<<gG64, blk, 0, stream>>>(A0hi, Wf_a, bf_a, out, NA, 64, 64);
    gemm_k<128, false, false, true ><<<gG64, blk, 0, stream>>>(fa, Wf_a + 64 * 64, nullptr, out, NA, 64, 64);
    gemm_k<64,  true,  false, false><<<gG64, blk, 0, stream>>>(A2hi, Wf_b, bf_b, out + (size_t)NA * OUTD, NB, 64, 64);
    gemm_k<128, false, false, true ><<<gG64, blk, 0, stream>>>(fb, Wf_b + 64 * 64, nullptr, out + (size_t)NA * OUTD, NB, 64, 64);
}

// Round 3
// 2941.669 us; speedup vs baseline: 6.0946x; 1.1419x over previous
//
#include <hip/hip_runtime.h>
#include <math.h>

#define NA 100000
#define NB 100000
#define NROW 100000   // all four relations have 100000 output rows
#define FT 128
#define H1 128
#define H2 64
#define OUTD 64

// ---------------- zero fill (used for CSR count arrays) ----------------
__global__ __launch_bounds__(256) void zero_k(float4* __restrict__ p, int n4) {
    int i = blockIdx.x * 256 + threadIdx.x;
    if (i < n4) p[i] = make_float4(0.f, 0.f, 0.f, 0.f);
}

// ---------------- CSR build: histogram ----------------
__global__ __launch_bounds__(256) void hist_k(const int* __restrict__ rows,
                                              int* __restrict__ cnt, int E) {
    int i = blockIdx.x * 256 + threadIdx.x;
    if (i < E) atomicAdd(&cnt[rows[i]], 1);
}

// ---------------- CSR build: exclusive scan (one block per relation) ----------------
__global__ __launch_bounds__(1024) void scan_k(const int* __restrict__ cnt4,
                                               int* __restrict__ rp4,
                                               int* __restrict__ cur4, int N) {
    __shared__ int sh[1024];
    const int r = blockIdx.x;
    const int* cnt = cnt4 + (size_t)r * N;
    int* rp  = rp4 + (size_t)r * (N + 1);
    int* cur = cur4 + (size_t)r * N;
    const int t = threadIdx.x;
    const int chunk = (N + 1023) / 1024;
    const int lo = t * chunk;
    const int hi = min(N, lo + chunk);
    int s = 0;
    for (int i = lo; i < hi; i++) s += cnt[i];
    sh[t] = s;
    __syncthreads();
    for (int off = 1; off < 1024; off <<= 1) {
        int v = (t >= off) ? sh[t - off] : 0;
        __syncthreads();
        sh[t] += v;
        __syncthreads();
    }
    int base = (t == 0) ? 0 : sh[t - 1];
    for (int i = lo; i < hi; i++) {
        rp[i] = base; cur[i] = base;
        base += cnt[i];
    }
    if (t == 1023) rp[N] = sh[1023];
}

// ---------------- CSR build: scatter (col,val) into row-sorted order ----------------
__global__ __launch_bounds__(256) void scatter_k(const int* __restrict__ rows,
                                                 const int* __restrict__ cols,
                                                 const float* __restrict__ vals,
                                                 int* __restrict__ cur,
                                                 int* __restrict__ colsS,
                                                 float* __restrict__ valsS, int E) {
    int i = blockIdx.x * 256 + threadIdx.x;
    if (i >= E) return;
    int r = rows[i];
    int pos = atomicAdd(&cur[r], 1);
    colsS[pos] = cols[i];
    valsS[pos] = vals[i];
}

// ---------------- SpMM (CSR gather), fused bias + LeakyReLU ----------------
// One wave per output row. F=128: float2/lane; F=64: float/lane.
template<int F>
__global__ __launch_bounds__(256) void spmm_csr_k(
    const int* __restrict__ rp, const int* __restrict__ colsS,
    const float* __restrict__ valsS, const float* __restrict__ X,
    const float* __restrict__ bias, float* __restrict__ out, int N)
{
    const int wid  = (blockIdx.x * 256 + threadIdx.x) >> 6;
    const int lane = threadIdx.x & 63;
    if (wid >= N) return;
    const int s = rp[wid];
    const int e = rp[wid + 1];

    if (F == 128) {
        float ax = 0.f, ay = 0.f;
        int j = s;
        for (; j + 3 < e; j += 4) {
            int c0 = colsS[j], c1 = colsS[j+1], c2 = colsS[j+2], c3 = colsS[j+3];
            float v0 = valsS[j], v1 = valsS[j+1], v2 = valsS[j+2], v3 = valsS[j+3];
            float2 x0 = *(const float2*)(X + (size_t)c0 * F + 2 * lane);
            float2 x1 = *(const float2*)(X + (size_t)c1 * F + 2 * lane);
            float2 x2 = *(const float2*)(X + (size_t)c2 * F + 2 * lane);
            float2 x3 = *(const float2*)(X + (size_t)c3 * F + 2 * lane);
            ax += v0 * x0.x + v1 * x1.x + v2 * x2.x + v3 * x3.x;
            ay += v0 * x0.y + v1 * x1.y + v2 * x2.y + v3 * x3.y;
        }
        for (; j < e; j++) {
            int c = colsS[j]; float v = valsS[j];
            float2 x = *(const float2*)(X + (size_t)c * F + 2 * lane);
            ax += v * x.x; ay += v * x.y;
        }
        ax += bias[2 * lane];
        ay += bias[2 * lane + 1];
        ax = ax > 0.f ? ax : 0.01f * ax;
        ay = ay > 0.f ? ay : 0.01f * ay;
        float2* dst = (float2*)(out + (size_t)wid * F + 2 * lane);
        *dst = make_float2(ax, ay);
    } else {
        float a = 0.f;
        int j = s;
        for (; j + 3 < e; j += 4) {
            int c0 = colsS[j], c1 = colsS[j+1], c2 = colsS[j+2], c3 = colsS[j+3];
            float v0 = valsS[j], v1 = valsS[j+1], v2 = valsS[j+2], v3 = valsS[j+3];
            a += v0 * X[(size_t)c0 * F + lane] + v1 * X[(size_t)c1 * F + lane]
               + v2 * X[(size_t)c2 * F + lane] + v3 * X[(size_t)c3 * F + lane];
        }
        for (; j < e; j++)
            a += valsS[j] * X[(size_t)colsS[j] * F + lane];
        a += bias[lane];
        a = a > 0.f ? a : 0.01f * a;
        out[(size_t)wid * F + lane] = a;
    }
}

// ---------------- GEMM: C = [act](A@W + [bias] [+ C]) ----------------
template<int KT, bool BIAS, bool ACT, bool ACCUM>
__global__ __launch_bounds__(256) void gemm_k(
    const float* __restrict__ A,
    const float* __restrict__ W,
    const float* __restrict__ bias,
    float* __restrict__ C,
    int M, int Nfull, int ldc)
{
    constexpr int BM = 64;
    constexpr int BN = 64;
    __shared__ float Ash[BM * KT];
    __shared__ float Wsh[KT * BN];

    const int t = threadIdx.x;
    const int row0 = blockIdx.x * BM;
    const int n0 = blockIdx.y * BN;

    for (int idx = t * 4; idx < BM * KT; idx += 256 * 4) {
        const int r = idx / KT;
        float4 v = make_float4(0.f, 0.f, 0.f, 0.f);
        if (row0 + r < M) v = *(const float4*)(A + (size_t)(row0 + r) * KT + (idx - r * KT));
        *(float4*)(Ash + idx) = v;
    }
    for (int idx = t; idx < KT * BN; idx += 256) {
        const int k = idx >> 6;
        const int n = idx & 63;
        Wsh[k * BN + (n ^ (k & 31))] = W[(size_t)k * Nfull + n0 + n];
    }
    __syncthreads();

    const int c  = t & 31;
    const int r0 = (t >> 5) * 8;

    float acc[8][2];
#pragma unroll
    for (int i = 0; i < 8; i++) { acc[i][0] = 0.f; acc[i][1] = 0.f; }

#pragma unroll 4
    for (int k = 0; k < KT; k += 4) {
        float4 a[8];
#pragma unroll
        for (int i = 0; i < 8; i++) a[i] = *(const float4*)(Ash + (r0 + i) * KT + k);
        float w[4][2];
#pragma unroll
        for (int kk = 0; kk < 4; kk++) {
            const int sw = (k + kk) & 31;
#pragma unroll
            for (int j = 0; j < 2; j++)
                w[kk][j] = Wsh[(k + kk) * BN + ((c + 32 * j) ^ sw)];
        }
#pragma unroll
        for (int i = 0; i < 8; i++) {
            acc[i][0] += a[i].x * w[0][0]; acc[i][1] += a[i].x * w[0][1];
            acc[i][0] += a[i].y * w[1][0]; acc[i][1] += a[i].y * w[1][1];
            acc[i][0] += a[i].z * w[2][0]; acc[i][1] += a[i].z * w[2][1];
            acc[i][0] += a[i].w * w[3][0]; acc[i][1] += a[i].w * w[3][1];
        }
    }

#pragma unroll
    for (int i = 0; i < 8; i++) {
        const int row = row0 + r0 + i;
        if (row < M) {
#pragma unroll
            for (int j = 0; j < 2; j++) {
                const int col = n0 + c + 32 * j;
                float v = acc[i][j];
                if (BIAS)  v += bias[col];
                if (ACCUM) v += C[(size_t)row * ldc + col];
                if (ACT)   v = (v > 0.f) ? v : 0.01f * v;
                C[(size_t)row * ldc + col] = v;
            }
        }
    }
}

// ---------------- semantic attention, block-tiled (LDS-staged) ----------------
// NT nodes per block. Stage g0/g1 tiles + W1 in LDS (coalesced float4),
// compute scores from LDS (broadcast reads), shuffle-reduce over j,
// softmax over P=2, coalesced float4 combine. In-place safe (eo==g0).
template<int D, int H, int NT, int LOGH>
__global__ __launch_bounds__(256) void att2_k(
    const float* __restrict__ g0, const float* __restrict__ g1,
    const float* __restrict__ W1, const float* __restrict__ b1,
    const float* __restrict__ W2, float* __restrict__ eo, int N)
{
    __shared__ float sg0[NT * D];
    __shared__ float sg1[NT * D];
    __shared__ float sW1[D * H];
    __shared__ float sw[2][NT];
    __shared__ float sbeta[2][NT];

    const int t = threadIdx.x;
    const int n0 = blockIdx.x * NT;
    constexpr int D4 = D / 4;

    for (int i = t; i < D * H; i += 256) sW1[i] = W1[i];
    for (int i = t; i < NT * D4; i += 256) {
        const int n = i / D4;
        float4 v0 = make_float4(0.f, 0.f, 0.f, 0.f), v1 = v0;
        if (n0 + n < N) {
            v0 = ((const float4*)(g0 + (size_t)(n0 + n) * D))[i - n * D4];
            v1 = ((const float4*)(g1 + (size_t)(n0 + n) * D))[i - n * D4];
        }
        ((float4*)sg0)[i] = v0;
        ((float4*)sg1)[i] = v1;
    }
    __syncthreads();

    constexpr int NPP = 256 / H;       // nodes scored per pass
    constexpr int PASSES = NT / NPP;
    const int j = t & (H - 1);
    const int nsub = t >> LOGH;
    const float b1j = b1[j];
    const float W2j = W2[j];

#pragma unroll
    for (int pass = 0; pass < PASSES; pass++) {
        const int n = pass * NPP + nsub;
#pragma unroll
        for (int p = 0; p < 2; p++) {
            const float* g = (p ? sg1 : sg0) + n * D;
            float s = b1j;
#pragma unroll 8
            for (int k = 0; k < D; k++) s += g[k] * sW1[k * H + j];
            float v = tanhf(s) * W2j;
#pragma unroll
            for (int m = 1; m < H; m <<= 1) v += __shfl_xor(v, m);
            if (j == 0) sw[p][n] = v;
        }
    }
    __syncthreads();
    if (t < NT) {
        const float w0 = sw[0][t], w1 = sw[1][t];
        const float mx = fmaxf(w0, w1);
        const float e0 = expf(w0 - mx), e1 = expf(w1 - mx);
        const float inv = 1.f / (e0 + e1);
        sbeta[0][t] = e0 * inv;
        sbeta[1][t] = e1 * inv;
    }
    __syncthreads();
    for (int i = t; i < NT * D4; i += 256) {
        const int n = i / D4;
        if (n0 + n < N) {
            const float4 a = ((const float4*)sg0)[i];
            const float4 b = ((const float4*)sg1)[i];
            const float c0 = sbeta[0][n], c1 = sbeta[1][n];
            float4 o;
            o.x = c0 * a.x + c1 * b.x;
            o.y = c0 * a.y + c1 * b.y;
            o.z = c0 * a.z + c1 * b.z;
            o.w = c0 * a.w + c1 * b.w;
            ((float4*)(eo + (size_t)(n0 + n) * D))[i - n * D4] = o;
        }
    }
}

// ---------------- launch ----------------
extern "C" void kernel_launch(void* const* d_in, const int* in_sizes, int n_in,
                              void* d_out, int out_size, void* d_ws, size_t ws_size,
                              hipStream_t stream)
{
    const float* feat = (const float*)d_in[0];
    const int*   row_aa = (const int*)d_in[1];
    const int*   col_aa = (const int*)d_in[2];
    const float* val_aa = (const float*)d_in[3];
    const int*   row_ab = (const int*)d_in[4];
    const int*   col_ab = (const int*)d_in[5];
    const float* val_ab = (const float*)d_in[6];
    const int*   row_ba = (const int*)d_in[7];
    const int*   col_ba = (const int*)d_in[8];
    const float* val_ba = (const float*)d_in[9];
    const int*   row_bb = (const int*)d_in[10];
    const int*   col_bb = (const int*)d_in[11];
    const float* val_bb = (const float*)d_in[12];
    const float* W0_aa = (const float*)d_in[13]; const float* b0_aa = (const float*)d_in[14];
    const float* W1_aa = (const float*)d_in[15]; const float* b1_aa = (const float*)d_in[16];
    const float* W0_ab = (const float*)d_in[17]; const float* b0_ab = (const float*)d_in[18];
    const float* W1_ab = (const float*)d_in[19]; const float* b1_ab = (const float*)d_in[20];
    const float* W0_ba = (const float*)d_in[21]; const float* b0_ba = (const float*)d_in[22];
    const float* W1_ba = (const float*)d_in[23]; const float* b1_ba = (const float*)d_in[24];
    const float* W0_bb = (const float*)d_in[25]; const float* b0_bb = (const float*)d_in[26];
    const float* W1_bb = (const float*)d_in[27]; const float* b1_bb = (const float*)d_in[28];
    const float* att0_a_W1 = (const float*)d_in[29];
    const float* att0_a_b1 = (const float*)d_in[30];
    const float* att0_a_W2 = (const float*)d_in[31];
    const float* att1_a_W1 = (const float*)d_in[32];
    const float* att1_a_b1 = (const float*)d_in[33];
    const float* att1_a_W2 = (const float*)d_in[34];
    const float* Wf_a = (const float*)d_in[35]; const float* bf_a = (const float*)d_in[36];
    const float* att0_b_W1 = (const float*)d_in[37];
    const float* att0_b_b1 = (const float*)d_in[38];
    const float* att0_b_W2 = (const float*)d_in[39];
    const float* att1_b_W1 = (const float*)d_in[40];
    const float* att1_b_b1 = (const float*)d_in[41];
    const float* att1_b_W2 = (const float*)d_in[42];
    const float* Wf_b = (const float*)d_in[43]; const float* bf_b = (const float*)d_in[44];

    const int E_r[4] = { in_sizes[1], in_sizes[4], in_sizes[7], in_sizes[10] };
    const int* rows_r[4] = { row_aa, row_ab, row_ba, row_bb };
    const int* cols_r[4] = { col_aa, col_ab, col_ba, col_bb };
    const float* vals_r[4] = { val_aa, val_ab, val_ba, val_bb };

    const size_t RSZ = (size_t)12800000;
    size_t Etot = (size_t)E_r[0] + E_r[1] + E_r[2] + E_r[3];
    size_t need = (3 * RSZ + (size_t)4 * (NROW + 1) + 8 * (size_t)NROW + 2 * Etot) * 4;
    if (ws_size < need) return;

    float* ws = (float*)d_ws;
    float* A0 = ws;
    float* A1 = ws + RSZ;
    float* A2 = ws + 2 * RSZ;
    float* A3 = (float*)d_out;            // e1_b lives here until final projection
    int*   rp4  = (int*)(ws + 3 * RSZ);
    int*   cnt4 = rp4 + (size_t)4 * (NROW + 1);
    int*   cur4 = cnt4 + (size_t)4 * NROW;
    int*   colsS = cur4 + (size_t)4 * NROW;
    float* valsS = (float*)(colsS + Etot);

    size_t eoff[4];
    eoff[0] = 0; eoff[1] = eoff[0] + E_r[0];
    eoff[2] = eoff[1] + E_r[1]; eoff[3] = eoff[2] + E_r[2];

    float* out = (float*)d_out;
    const float* fa = feat;
    const float* fb = feat + (size_t)NA * FT;

    const dim3 blk(256);
    const dim3 gG(1563, 2);       // GEMM M=100000, N=128
    const dim3 gG64(1563, 1);     // GEMM M=100000, N=64
    const int spg = (NROW * 64 + 255) / 256;   // spmm: one wave per row
    const int ag128 = (NROW + 15) / 16;        // att2 D=128, NT=16
    const int ag64  = (NROW + 31) / 32;        // att2 D=64,  NT=32

    // ================= build CSR for all 4 relations =================
    zero_k<<<(4 * NROW / 4 + 255) / 256, blk, 0, stream>>>((float4*)cnt4, 4 * NROW / 4);
    for (int r = 0; r < 4; r++)
        hist_k<<<(E_r[r] + 255) / 256, blk, 0, stream>>>(rows_r[r], cnt4 + (size_t)r * NROW, E_r[r]);
    scan_k<<<4, 1024, 0, stream>>>(cnt4, rp4, cur4, NROW);
    for (int r = 0; r < 4; r++)
        scatter_k<<<(E_r[r] + 255) / 256, blk, 0, stream>>>(
            rows_r[r], cols_r[r], vals_r[r], cur4 + (size_t)r * NROW,
            colsS + eoff[r], valsS + eoff[r], E_r[r]);

    const int* rp_aa = rp4;
    const int* rp_ab = rp4 + (NROW + 1);
    const int* rp_ba = rp4 + 2 * (NROW + 1);
    const int* rp_bb = rp4 + 3 * (NROW + 1);
    const int* cs_aa = colsS + eoff[0]; const float* vs_aa = valsS + eoff[0];
    const int* cs_ab = colsS + eoff[1]; const float* vs_ab = valsS + eoff[1];
    const int* cs_ba = colsS + eoff[2]; const float* vs_ba = valsS + eoff[2];
    const int* cs_bb = colsS + eoff[3]; const float* vs_bb = valsS + eoff[3];

    // ================= layer 0, type a =================
    gemm_k<128, false, false, false><<<gG, blk, 0, stream>>>(fa, W0_aa, nullptr, A0, NA, 128, 128);
    spmm_csr_k<128><<<spg, blk, 0, stream>>>(rp_aa, cs_aa, vs_aa, A0, b0_aa, A1, NA);
    gemm_k<128, false, false, false><<<gG, blk, 0, stream>>>(fb, W0_ab, nullptr, A0, NB, 128, 128);
    spmm_csr_k<128><<<spg, blk, 0, stream>>>(rp_ab, cs_ab, vs_ab, A0, b0_ab, A2, NA);
    att2_k<128, 32, 16, 5><<<ag128, blk, 0, stream>>>(A1, A2, att0_a_W1, att0_a_b1, att0_a_W2, A1, NA);
    // e1_a in A1

    // ================= layer 0, type b =================
    gemm_k<128, false, false, false><<<gG, blk, 0, stream>>>(fa, W0_ba, nullptr, A0, NA, 128, 128);
    spmm_csr_k<128><<<spg, blk, 0, stream>>>(rp_ba, cs_ba, vs_ba, A0, b0_ba, A3, NB);
    gemm_k<128, false, false, false><<<gG, blk, 0, stream>>>(fb, W0_bb, nullptr, A0, NB, 128, 128);
    spmm_csr_k<128><<<spg, blk, 0, stream>>>(rp_bb, cs_bb, vs_bb, A0, b0_bb, A2, NB);
    att2_k<128, 32, 16, 5><<<ag128, blk, 0, stream>>>(A3, A2, att0_b_W1, att0_b_b1, att0_b_W2, A3, NB);
    // e1_b in A3 (= d_out region)

    float* A0lo = A0;            float* A0hi = A0 + RSZ / 2;
    float* A2lo = A2;            float* A2hi = A2 + RSZ / 2;

    // ================= layer 1, type a =================
    gemm_k<128, false, false, false><<<gG64, blk, 0, stream>>>(A1, W1_aa, nullptr, A0lo, NA, 64, 64);
    spmm_csr_k<64><<<spg, blk, 0, stream>>>(rp_aa, cs_aa, vs_aa, A0lo, b1_aa, A0hi, NA);
    gemm_k<128, false, false, false><<<gG64, blk, 0, stream>>>(A3, W1_ab, nullptr, A2lo, NB, 64, 64);
    spmm_csr_k<64><<<spg, blk, 0, stream>>>(rp_ab, cs_ab, vs_ab, A2lo, b1_ab, A2hi, NA);
    att2_k<64, 16, 32, 4><<<ag64, blk, 0, stream>>>(A0hi, A2hi, att1_a_W1, att1_a_b1, att1_a_W2, A0hi, NA);
    // u_a in A0hi

    // ================= layer 1, type b =================
    gemm_k<128, false, false, false><<<gG64, blk, 0, stream>>>(A1, W1_ba, nullptr, A2lo, NA, 64, 64);
    spmm_csr_k<64><<<spg, blk, 0, stream>>>(rp_ba, cs_ba, vs_ba, A2lo, b1_ba, A2hi, NB);
    gemm_k<128, false, false, false><<<gG64, blk, 0, stream>>>(A3, W1_bb, nullptr, A2lo, NB, 64, 64);
    spmm_csr_k<64><<<spg, blk, 0, stream>>>(rp_bb, cs_bb, vs_bb, A2lo, b1_bb, A0lo, NB);
    att2_k<64, 16, 32, 4><<<ag64, blk, 0, stream>>>(A2hi, A0lo, att1_b_W1, att1_b_b1, att1_b_W2, A2hi, NB);
    // u_b in A2hi

    // ================= final projection =================
    gemm_k<64,  true,  false, false><<<gG64, blk, 0, stream>>>(A0hi, Wf_a, bf_a, out, NA, 64, 64);
    gemm_k<128, false, false, true ><<<gG64, blk, 0, stream>>>(fa, Wf_a + 64 * 64, nullptr, out, NA, 64, 64);
    gemm_k<64,  true,  false, false><<<gG64, blk, 0, stream>>>(A2hi, Wf_b, bf_b, out + (size_t)NA * OUTD, NB, 64, 64);
    gemm_k<128, false, false, true ><<<gG64, blk, 0, stream>>>(fb, Wf_b + 64 * 64, nullptr, out + (size_t)NA * OUTD, NB, 64, 64);
}

// Round 4
// 2728.364 us; speedup vs baseline: 6.5711x; 1.0782x over previous
//
#include <hip/hip_runtime.h>
#include <math.h>

#define NA 100000
#define NB 100000
#define NROW 100000   // all four relations have 100000 output rows
#define FT 128
#define H1 128
#define H2 64
#define OUTD 64
#define SCHUNK 4096   // elements per scan block

// ---------------- zero fill (used for CSR count arrays) ----------------
__global__ __launch_bounds__(256) void zero_k(float4* __restrict__ p, int n4) {
    int i = blockIdx.x * 256 + threadIdx.x;
    if (i < n4) p[i] = make_float4(0.f, 0.f, 0.f, 0.f);
}

// ---------------- CSR build: histogram ----------------
__global__ __launch_bounds__(256) void hist_k(const int* __restrict__ rows,
                                              int* __restrict__ cnt, int E) {
    int i = blockIdx.x * 256 + threadIdx.x;
    if (i < E) atomicAdd(&cnt[rows[i]], 1);
}

// ---------------- multi-block segmented exclusive scan ----------------
// phase 1: per-block sums (grid = 4 * bpr)
__global__ __launch_bounds__(256) void scan1_k(const int* __restrict__ cnt4,
                                               int* __restrict__ bsum, int N, int bpr) {
    const int r = blockIdx.x / bpr;
    const int b = blockIdx.x - r * bpr;
    const int* cnt = cnt4 + (size_t)r * N + (size_t)b * SCHUNK;
    const int count = min(SCHUNK, N - b * SCHUNK);
    const int t = threadIdx.x;
    int s = 0;
    for (int i = t; i < count; i += 256) s += cnt[i];
#pragma unroll
    for (int m = 1; m < 64; m <<= 1) s += __shfl_xor(s, m);
    __shared__ int sh[4];
    if ((t & 63) == 0) sh[t >> 6] = s;
    __syncthreads();
    if (t == 0) bsum[blockIdx.x] = sh[0] + sh[1] + sh[2] + sh[3];
}

// phase 2: exclusive scan of block sums, one wave per relation (bpr <= 64)
__global__ __launch_bounds__(256) void scan2_k(int* __restrict__ bsum, int bpr) {
    const int lane = threadIdx.x & 63;
    const int r = threadIdx.x >> 6;
    int v = (lane < bpr) ? bsum[r * bpr + lane] : 0;
    int inc = v;
#pragma unroll
    for (int m = 1; m < 64; m <<= 1) {
        int u = __shfl_up(inc, m);
        if (lane >= m) inc += u;
    }
    if (lane < bpr) bsum[r * bpr + lane] = inc - v;
}

// phase 3: per-block local scan + offset, write rp & cur (grid = 4 * bpr)
__global__ __launch_bounds__(256) void scan3_k(const int* __restrict__ cnt4,
                                               const int* __restrict__ bsum,
                                               int* __restrict__ rp4,
                                               int* __restrict__ cur4, int N, int bpr) {
    const int r = blockIdx.x / bpr;
    const int b = blockIdx.x - r * bpr;
    const int base0 = b * SCHUNK;
    const int* cnt = cnt4 + (size_t)r * N;
    int* rp  = rp4  + (size_t)r * (N + 1);
    int* cur = cur4 + (size_t)r * N;
    const int count = min(SCHUNK, N - base0);
    const int t = threadIdx.x;
    const int off = base0 + t * 16;

    int v[16];
    int tot = 0;
#pragma unroll
    for (int i = 0; i < 16; i++) {
        const int idx = off + i;
        v[i] = (idx < base0 + count) ? cnt[idx] : 0;
        tot += v[i];
    }
    // wave inclusive scan of per-thread totals
    int inc = tot;
#pragma unroll
    for (int m = 1; m < 64; m <<= 1) {
        int u = __shfl_up(inc, m);
        if ((t & 63) >= m) inc += u;
    }
    __shared__ int wsum[4];
    if ((t & 63) == 63) wsum[t >> 6] = inc;
    __syncthreads();
    int wbase = 0;
    const int w = t >> 6;
    for (int i = 0; i < 4; i++) if (i < w) wbase += wsum[i];

    int ex = inc - tot + wbase + bsum[blockIdx.x];
#pragma unroll
    for (int i = 0; i < 16; i++) {
        const int idx = off + i;
        if (idx < base0 + count) {
            rp[idx] = ex; cur[idx] = ex;
            ex += v[i];
        }
    }
    if (N - 1 >= off && N - 1 < off + 16) rp[N] = ex;
}

// ---------------- CSR build: scatter (col,val) into row-sorted order ----------------
__global__ __launch_bounds__(256) void scatter_k(const int* __restrict__ rows,
                                                 const int* __restrict__ cols,
                                                 const float* __restrict__ vals,
                                                 int* __restrict__ cur,
                                                 int* __restrict__ colsS,
                                                 float* __restrict__ valsS, int E) {
    int i = blockIdx.x * 256 + threadIdx.x;
    if (i >= E) return;
    int r = rows[i];
    int pos = atomicAdd(&cur[r], 1);
    colsS[pos] = cols[i];
    valsS[pos] = vals[i];
}

// ---------------- SpMM (CSR gather), fused bias + LeakyReLU ----------------
// One wave per output row. F=128: float2/lane; F=64: float/lane.
template<int F>
__global__ __launch_bounds__(256) void spmm_csr_k(
    const int* __restrict__ rp, const int* __restrict__ colsS,
    const float* __restrict__ valsS, const float* __restrict__ X,
    const float* __restrict__ bias, float* __restrict__ out, int N)
{
    const int wid  = (blockIdx.x * 256 + threadIdx.x) >> 6;
    const int lane = threadIdx.x & 63;
    if (wid >= N) return;
    const int s = rp[wid];
    const int e = rp[wid + 1];

    if (F == 128) {
        float ax = 0.f, ay = 0.f;
        int j = s;
        for (; j + 3 < e; j += 4) {
            int c0 = colsS[j], c1 = colsS[j+1], c2 = colsS[j+2], c3 = colsS[j+3];
            float v0 = valsS[j], v1 = valsS[j+1], v2 = valsS[j+2], v3 = valsS[j+3];
            float2 x0 = *(const float2*)(X + (size_t)c0 * F + 2 * lane);
            float2 x1 = *(const float2*)(X + (size_t)c1 * F + 2 * lane);
            float2 x2 = *(const float2*)(X + (size_t)c2 * F + 2 * lane);
            float2 x3 = *(const float2*)(X + (size_t)c3 * F + 2 * lane);
            ax += v0 * x0.x + v1 * x1.x + v2 * x2.x + v3 * x3.x;
            ay += v0 * x0.y + v1 * x1.y + v2 * x2.y + v3 * x3.y;
        }
        for (; j < e; j++) {
            int c = colsS[j]; float v = valsS[j];
            float2 x = *(const float2*)(X + (size_t)c * F + 2 * lane);
            ax += v * x.x; ay += v * x.y;
        }
        ax += bias[2 * lane];
        ay += bias[2 * lane + 1];
        ax = ax > 0.f ? ax : 0.01f * ax;
        ay = ay > 0.f ? ay : 0.01f * ay;
        float2* dst = (float2*)(out + (size_t)wid * F + 2 * lane);
        *dst = make_float2(ax, ay);
    } else {
        float a = 0.f;
        int j = s;
        for (; j + 3 < e; j += 4) {
            int c0 = colsS[j], c1 = colsS[j+1], c2 = colsS[j+2], c3 = colsS[j+3];
            float v0 = valsS[j], v1 = valsS[j+1], v2 = valsS[j+2], v3 = valsS[j+3];
            a += v0 * X[(size_t)c0 * F + lane] + v1 * X[(size_t)c1 * F + lane]
               + v2 * X[(size_t)c2 * F + lane] + v3 * X[(size_t)c3 * F + lane];
        }
        for (; j < e; j++)
            a += valsS[j] * X[(size_t)colsS[j] * F + lane];
        a += bias[lane];
        a = a > 0.f ? a : 0.01f * a;
        out[(size_t)wid * F + lane] = a;
    }
}

// ---------------- GEMM: C = [act](A@W + [bias] [+ C]) ----------------
template<int KT, bool BIAS, bool ACT, bool ACCUM>
__global__ __launch_bounds__(256) void gemm_k(
    const float* __restrict__ A,
    const float* __restrict__ W,
    const float* __restrict__ bias,
    float* __restrict__ C,
    int M, int Nfull, int ldc)
{
    constexpr int BM = 64;
    constexpr int BN = 64;
    __shared__ float Ash[BM * KT];
    __shared__ float Wsh[KT * BN];

    const int t = threadIdx.x;
    const int row0 = blockIdx.x * BM;
    const int n0 = blockIdx.y * BN;

    for (int idx = t * 4; idx < BM * KT; idx += 256 * 4) {
        const int r = idx / KT;
        float4 v = make_float4(0.f, 0.f, 0.f, 0.f);
        if (row0 + r < M) v = *(const float4*)(A + (size_t)(row0 + r) * KT + (idx - r * KT));
        *(float4*)(Ash + idx) = v;
    }
    for (int idx = t; idx < KT * BN; idx += 256) {
        const int k = idx >> 6;
        const int n = idx & 63;
        Wsh[k * BN + (n ^ (k & 31))] = W[(size_t)k * Nfull + n0 + n];
    }
    __syncthreads();

    const int c  = t & 31;
    const int r0 = (t >> 5) * 8;

    float acc[8][2];
#pragma unroll
    for (int i = 0; i < 8; i++) { acc[i][0] = 0.f; acc[i][1] = 0.f; }

#pragma unroll 4
    for (int k = 0; k < KT; k += 4) {
        float4 a[8];
#pragma unroll
        for (int i = 0; i < 8; i++) a[i] = *(const float4*)(Ash + (r0 + i) * KT + k);
        float w[4][2];
#pragma unroll
        for (int kk = 0; kk < 4; kk++) {
            const int sw = (k + kk) & 31;
#pragma unroll
            for (int j = 0; j < 2; j++)
                w[kk][j] = Wsh[(k + kk) * BN + ((c + 32 * j) ^ sw)];
        }
#pragma unroll
        for (int i = 0; i < 8; i++) {
            acc[i][0] += a[i].x * w[0][0]; acc[i][1] += a[i].x * w[0][1];
            acc[i][0] += a[i].y * w[1][0]; acc[i][1] += a[i].y * w[1][1];
            acc[i][0] += a[i].z * w[2][0]; acc[i][1] += a[i].z * w[2][1];
            acc[i][0] += a[i].w * w[3][0]; acc[i][1] += a[i].w * w[3][1];
        }
    }

#pragma unroll
    for (int i = 0; i < 8; i++) {
        const int row = row0 + r0 + i;
        if (row < M) {
#pragma unroll
            for (int j = 0; j < 2; j++) {
                const int col = n0 + c + 32 * j;
                float v = acc[i][j];
                if (BIAS)  v += bias[col];
                if (ACCUM) v += C[(size_t)row * ldc + col];
                if (ACT)   v = (v > 0.f) ? v : 0.01f * v;
                C[(size_t)row * ldc + col] = v;
            }
        }
    }
}

// ---------------- semantic attention, block-tiled (LDS-staged) ----------------
template<int D, int H, int NT, int LOGH>
__global__ __launch_bounds__(256) void att2_k(
    const float* __restrict__ g0, const float* __restrict__ g1,
    const float* __restrict__ W1, const float* __restrict__ b1,
    const float* __restrict__ W2, float* __restrict__ eo, int N)
{
    __shared__ float sg0[NT * D];
    __shared__ float sg1[NT * D];
    __shared__ float sW1[D * H];
    __shared__ float sw[2][NT];
    __shared__ float sbeta[2][NT];

    const int t = threadIdx.x;
    const int n0 = blockIdx.x * NT;
    constexpr int D4 = D / 4;

    for (int i = t; i < D * H; i += 256) sW1[i] = W1[i];
    for (int i = t; i < NT * D4; i += 256) {
        const int n = i / D4;
        float4 v0 = make_float4(0.f, 0.f, 0.f, 0.f), v1 = v0;
        if (n0 + n < N) {
            v0 = ((const float4*)(g0 + (size_t)(n0 + n) * D))[i - n * D4];
            v1 = ((const float4*)(g1 + (size_t)(n0 + n) * D))[i - n * D4];
        }
        ((float4*)sg0)[i] = v0;
        ((float4*)sg1)[i] = v1;
    }
    __syncthreads();

    constexpr int NPP = 256 / H;
    constexpr int PASSES = NT / NPP;
    const int j = t & (H - 1);
    const int nsub = t >> LOGH;
    const float b1j = b1[j];
    const float W2j = W2[j];

#pragma unroll
    for (int pass = 0; pass < PASSES; pass++) {
        const int n = pass * NPP + nsub;
#pragma unroll
        for (int p = 0; p < 2; p++) {
            const float* g = (p ? sg1 : sg0) + n * D;
            float s = b1j;
#pragma unroll 8
            for (int k = 0; k < D; k++) s += g[k] * sW1[k * H + j];
            float v = tanhf(s) * W2j;
#pragma unroll
            for (int m = 1; m < H; m <<= 1) v += __shfl_xor(v, m);
            if (j == 0) sw[p][n] = v;
        }
    }
    __syncthreads();
    if (t < NT) {
        const float w0 = sw[0][t], w1 = sw[1][t];
        const float mx = fmaxf(w0, w1);
        const float e0 = expf(w0 - mx), e1 = expf(w1 - mx);
        const float inv = 1.f / (e0 + e1);
        sbeta[0][t] = e0 * inv;
        sbeta[1][t] = e1 * inv;
    }
    __syncthreads();
    for (int i = t; i < NT * D4; i += 256) {
        const int n = i / D4;
        if (n0 + n < N) {
            const float4 a = ((const float4*)sg0)[i];
            const float4 b = ((const float4*)sg1)[i];
            const float c0 = sbeta[0][n], c1 = sbeta[1][n];
            float4 o;
            o.x = c0 * a.x + c1 * b.x;
            o.y = c0 * a.y + c1 * b.y;
            o.z = c0 * a.z + c1 * b.z;
            o.w = c0 * a.w + c1 * b.w;
            ((float4*)(eo + (size_t)(n0 + n) * D))[i - n * D4] = o;
        }
    }
}

// ---------------- launch ----------------
extern "C" void kernel_launch(void* const* d_in, const int* in_sizes, int n_in,
                              void* d_out, int out_size, void* d_ws, size_t ws_size,
                              hipStream_t stream)
{
    const float* feat = (const float*)d_in[0];
    const int*   row_aa = (const int*)d_in[1];
    const int*   col_aa = (const int*)d_in[2];
    const float* val_aa = (const float*)d_in[3];
    const int*   row_ab = (const int*)d_in[4];
    const int*   col_ab = (const int*)d_in[5];
    const float* val_ab = (const float*)d_in[6];
    const int*   row_ba = (const int*)d_in[7];
    const int*   col_ba = (const int*)d_in[8];
    const float* val_ba = (const float*)d_in[9];
    const int*   row_bb = (const int*)d_in[10];
    const int*   col_bb = (const int*)d_in[11];
    const float* val_bb = (const float*)d_in[12];
    const float* W0_aa = (const float*)d_in[13]; const float* b0_aa = (const float*)d_in[14];
    const float* W1_aa = (const float*)d_in[15]; const float* b1_aa = (const float*)d_in[16];
    const float* W0_ab = (const float*)d_in[17]; const float* b0_ab = (const float*)d_in[18];
    const float* W1_ab = (const float*)d_in[19]; const float* b1_ab = (const float*)d_in[20];
    const float* W0_ba = (const float*)d_in[21]; const float* b0_ba = (const float*)d_in[22];
    const float* W1_ba = (const float*)d_in[23]; const float* b1_ba = (const float*)d_in[24];
    const float* W0_bb = (const float*)d_in[25]; const float* b0_bb = (const float*)d_in[26];
    const float* W1_bb = (const float*)d_in[27]; const float* b1_bb = (const float*)d_in[28];
    const float* att0_a_W1 = (const float*)d_in[29];
    const float* att0_a_b1 = (const float*)d_in[30];
    const float* att0_a_W2 = (const float*)d_in[31];
    const float* att1_a_W1 = (const float*)d_in[32];
    const float* att1_a_b1 = (const float*)d_in[33];
    const float* att1_a_W2 = (const float*)d_in[34];
    const float* Wf_a = (const float*)d_in[35]; const float* bf_a = (const float*)d_in[36];
    const float* att0_b_W1 = (const float*)d_in[37];
    const float* att0_b_b1 = (const float*)d_in[38];
    const float* att0_b_W2 = (const float*)d_in[39];
    const float* att1_b_W1 = (const float*)d_in[40];
    const float* att1_b_b1 = (const float*)d_in[41];
    const float* att1_b_W2 = (const float*)d_in[42];
    const float* Wf_b = (const float*)d_in[43]; const float* bf_b = (const float*)d_in[44];

    const int E_r[4] = { in_sizes[1], in_sizes[4], in_sizes[7], in_sizes[10] };
    const int* rows_r[4] = { row_aa, row_ab, row_ba, row_bb };
    const int* cols_r[4] = { col_aa, col_ab, col_ba, col_bb };
    const float* vals_r[4] = { val_aa, val_ab, val_ba, val_bb };

    const size_t RSZ = (size_t)12800000;
    size_t Etot = (size_t)E_r[0] + E_r[1] + E_r[2] + E_r[3];
    const int bpr = (NROW + SCHUNK - 1) / SCHUNK;      // blocks per relation (25)
    size_t need = (3 * RSZ + (size_t)4 * (NROW + 1) + 8 * (size_t)NROW
                   + (size_t)4 * bpr + 2 * Etot) * 4;
    if (ws_size < need) return;

    float* ws = (float*)d_ws;
    float* A0 = ws;
    float* A1 = ws + RSZ;
    float* A2 = ws + 2 * RSZ;
    float* A3 = (float*)d_out;            // e1_b lives here until final projection
    int*   rp4  = (int*)(ws + 3 * RSZ);
    int*   cnt4 = rp4 + (size_t)4 * (NROW + 1);
    int*   cur4 = cnt4 + (size_t)4 * NROW;
    int*   bsum = cur4 + (size_t)4 * NROW;
    int*   colsS = bsum + (size_t)4 * bpr;
    float* valsS = (float*)(colsS + Etot);

    size_t eoff[4];
    eoff[0] = 0; eoff[1] = eoff[0] + E_r[0];
    eoff[2] = eoff[1] + E_r[1]; eoff[3] = eoff[2] + E_r[2];

    float* out = (float*)d_out;
    const float* fa = feat;
    const float* fb = feat + (size_t)NA * FT;

    const dim3 blk(256);
    const dim3 gG(1563, 2);       // GEMM M=100000, N=128
    const dim3 gG64(1563, 1);     // GEMM M=100000, N=64
    const int spg = (NROW * 64 + 255) / 256;   // spmm: one wave per row
    const int ag128 = (NROW + 15) / 16;        // att2 D=128, NT=16
    const int ag64  = (NROW + 31) / 32;        // att2 D=64,  NT=32

    // ================= build CSR for all 4 relations =================
    zero_k<<<(4 * NROW / 4 + 255) / 256, blk, 0, stream>>>((float4*)cnt4, 4 * NROW / 4);
    for (int r = 0; r < 4; r++)
        hist_k<<<(E_r[r] + 255) / 256, blk, 0, stream>>>(rows_r[r], cnt4 + (size_t)r * NROW, E_r[r]);
    scan1_k<<<4 * bpr, blk, 0, stream>>>(cnt4, bsum, NROW, bpr);
    scan2_k<<<1, blk, 0, stream>>>(bsum, bpr);
    scan3_k<<<4 * bpr, blk, 0, stream>>>(cnt4, bsum, rp4, cur4, NROW, bpr);
    for (int r = 0; r < 4; r++)
        scatter_k<<<(E_r[r] + 255) / 256, blk, 0, stream>>>(
            rows_r[r], cols_r[r], vals_r[r], cur4 + (size_t)r * NROW,
            colsS + eoff[r], valsS + eoff[r], E_r[r]);

    const int* rp_aa = rp4;
    const int* rp_ab = rp4 + (NROW + 1);
    const int* rp_ba = rp4 + 2 * (NROW + 1);
    const int* rp_bb = rp4 + 3 * (NROW + 1);
    const int* cs_aa = colsS + eoff[0]; const float* vs_aa = valsS + eoff[0];
    const int* cs_ab = colsS + eoff[1]; const float* vs_ab = valsS + eoff[1];
    const int* cs_ba = colsS + eoff[2]; const float* vs_ba = valsS + eoff[2];
    const int* cs_bb = colsS + eoff[3]; const float* vs_bb = valsS + eoff[3];

    // ================= layer 0, type a =================
    gemm_k<128, false, false, false><<<gG, blk, 0, stream>>>(fa, W0_aa, nullptr, A0, NA, 128, 128);
    spmm_csr_k<128><<<spg, blk, 0, stream>>>(rp_aa, cs_aa, vs_aa, A0, b0_aa, A1, NA);
    gemm_k<128, false, false, false><<<gG, blk, 0, stream>>>(fb, W0_ab, nullptr, A0, NB, 128, 128);
    spmm_csr_k<128><<<spg, blk, 0, stream>>>(rp_ab, cs_ab, vs_ab, A0, b0_ab, A2, NA);
    att2_k<128, 32, 16, 5><<<ag128, blk, 0, stream>>>(A1, A2, att0_a_W1, att0_a_b1, att0_a_W2, A1, NA);
    // e1_a in A1

    // ================= layer 0, type b =================
    gemm_k<128, false, false, false><<<gG, blk, 0, stream>>>(fa, W0_ba, nullptr, A0, NA, 128, 128);
    spmm_csr_k<128><<<spg, blk, 0, stream>>>(rp_ba, cs_ba, vs_ba, A0, b0_ba, A3, NB);
    gemm_k<128, false, false, false><<<gG, blk, 0, stream>>>(fb, W0_bb, nullptr, A0, NB, 128, 128);
    spmm_csr_k<128><<<spg, blk, 0, stream>>>(rp_bb, cs_bb, vs_bb, A0, b0_bb, A2, NB);
    att2_k<128, 32, 16, 5><<<ag128, blk, 0, stream>>>(A3, A2, att0_b_W1, att0_b_b1, att0_b_W2, A3, NB);
    // e1_b in A3 (= d_out region)

    float* A0lo = A0;            float* A0hi = A0 + RSZ / 2;
    float* A2lo = A2;            float* A2hi = A2 + RSZ / 2;

    // ================= layer 1, type a =================
    gemm_k<128, false, false, false><<<gG64, blk, 0, stream>>>(A1, W1_aa, nullptr, A0lo, NA, 64, 64);
    spmm_csr_k<64><<<spg, blk, 0, stream>>>(rp_aa, cs_aa, vs_aa, A0lo, b1_aa, A0hi, NA);
    gemm_k<128, false, false, false><<<gG64, blk, 0, stream>>>(A3, W1_ab, nullptr, A2lo, NB, 64, 64);
    spmm_csr_k<64><<<spg, blk, 0, stream>>>(rp_ab, cs_ab, vs_ab, A2lo, b1_ab, A2hi, NA);
    att2_k<64, 16, 32, 4><<<ag64, blk, 0, stream>>>(A0hi, A2hi, att1_a_W1, att1_a_b1, att1_a_W2, A0hi, NA);
    // u_a in A0hi

    // ================= layer 1, type b =================
    gemm_k<128, false, false, false><<<gG64, blk, 0, stream>>>(A1, W1_ba, nullptr, A2lo, NA, 64, 64);
    spmm_csr_k<64><<<spg, blk, 0, stream>>>(rp_ba, cs_ba, vs_ba, A2lo, b1_ba, A2hi, NB);
    gemm_k<128, false, false, false><<<gG64, blk, 0, stream>>>(A3, W1_bb, nullptr, A2lo, NB, 64, 64);
    spmm_csr_k<64><<<spg, blk, 0, stream>>>(rp_bb, cs_bb, vs_bb, A2lo, b1_bb, A0lo, NB);
    att2_k<64, 16, 32, 4><<<ag64, blk, 0, stream>>>(A2hi, A0lo, att1_b_W1, att1_b_b1, att1_b_W2, A2hi, NB);
    // u_b in A2hi

    // ================= final projection =================
    gemm_k<64,  true,  false, false><<<gG64, blk, 0, stream>>>(A0hi, Wf_a, bf_a, out, NA, 64, 64);
    gemm_k<128, false, false, true ><<<gG64, blk, 0, stream>>>(fa, Wf_a + 64 * 64, nullptr, out, NA, 64, 64);
    gemm_k<64,  true,  false, false><<<gG64, blk, 0, stream>>>(A2hi, Wf_b, bf_b, out + (size_t)NA * OUTD, NB, 64, 64);
    gemm_k<128, false, false, true ><<<gG64, blk, 0, stream>>>(fb, Wf_b + 64 * 64, nullptr, out + (size_t)NA * OUTD, NB, 64, 64);
}